// Round 16
// baseline (185.578 us; speedup 1.0000x reference)
//
#include <hip/hip_runtime.h>

#define DIM 768
#define NHEADS 12
#define HDIM 64
#define BATCH 2
#define SEQ 2048
#define ROWS (BATCH*SEQ)   // 4096
#define KSPLIT 4

typedef __attribute__((ext_vector_type(8))) _Float16 f16x8;
typedef __attribute__((ext_vector_type(4))) _Float16 f16x4;
typedef __attribute__((ext_vector_type(2))) _Float16 f16x2;
typedef __attribute__((ext_vector_type(4))) float    f32x4;

// async global->LDS DMA, 16 B per lane; LDS dest must be wave-uniform base
__device__ __forceinline__ void dma16(const _Float16* g, _Float16* l) {
    __builtin_amdgcn_global_load_lds(
        (const __attribute__((address_space(1))) unsigned int*)g,
        (__attribute__((address_space(3))) unsigned int*)l, 16, 0, 0);
}

// ============================================================
// Fragment layout F(mt, kt): 16 rows x 32 cols of row-major M[R][C]:
//   frag[lane][j] = M[mt*16 + (lane&15)][kt*32 + (lane>>4)*8 + j]
// stored at dst[((mt*(C/32) + kt)*64 + lane)*8] (halves).
// V tile layout (for 16x16x16 PV MFMA): per 16-key chunk kc,
//   Vkt[((kc*48 + (h*4+dt))*64 + lane)*4] : tile[lane][j] =
//   V[d = (h*4+dt)*16 + (lane&15)][key = kc*16 + (lane>>4)*4 + j]
// ============================================================

// ---- all 4 fp32->f16 frag conversions in one launch (all have C=768) ----
// Wq is pre-scaled by log2(e): QK^T scores land in log2 domain, so the
// softmax exp is a single v_exp_f32 (2^x). Wq feeds ONLY Q. (verified v4/v5)
__global__ __launch_bounds__(256) void cvt_all(
    const float* __restrict__ x,  const float* __restrict__ wq,
    const float* __restrict__ wk, const float* __restrict__ wv,
    _Float16* __restrict__ xf,  _Float16* __restrict__ wqf,
    _Float16* __restrict__ wkf, _Float16* __restrict__ wvf)
{
    const int lane = threadIdx.x & 63;
    const int wid  = (blockIdx.x * 256 + threadIdx.x) >> 6;
    const float* src; _Float16* dst; int t;
    float sc = 1.0f;
    if (wid < 6144)      { src = x;  dst = xf;  t = wid;        }
    else if (wid < 7296) { src = wq; dst = wqf; t = wid - 6144; sc = 1.4426950408889634f; }
    else if (wid < 8448) { src = wk; dst = wkf; t = wid - 7296; }
    else                 { src = wv; dst = wvf; t = wid - 8448; }
    const int c = lane & 15, quad = lane >> 4;
    const int mt = t / 24, kt = t % 24;
    const float* p = src + (size_t)(mt*16 + c) * 768 + kt*32 + quad*8;
    float4 v0 = *(const float4*)p;
    float4 v1 = *(const float4*)(p + 4);
    f16x8 o;
    o[0]=(_Float16)(v0.x*sc); o[1]=(_Float16)(v0.y*sc); o[2]=(_Float16)(v0.z*sc); o[3]=(_Float16)(v0.w*sc);
    o[4]=(_Float16)(v1.x*sc); o[5]=(_Float16)(v1.y*sc); o[6]=(_Float16)(v1.z*sc); o[7]=(_Float16)(v1.w*sc);
    *reinterpret_cast<f16x8*>(dst + ((size_t)t * 64 + lane) * 8) = o;
}

// ---- all 3 projections, v15: barrier-free register-direct GEMM ----
// Diagnosis: the staged version ran at ~11% MFMA util — per-K-step barrier
// with 1-2 blocks/CU serializes the CU (same disease as attn's lockstep).
// Inputs are L2-resident (xf 6.3MB + weights 3.5MB) and the fragment layout
// makes every frag a coalesced 1KB line, so: NO LDS staging, NO barriers.
// Each wave owns one output tile and streams its A/B frags global->register
// with one-step prefetch (attn's proven vv pattern; v7's failure was zero
// prefetch + barriers — both absent here). Waves free-run.
// bid < 256: QK, wave = 64 rows x 96 cols of C = x*[Wq;Wk]^T (acc[4][6])
// bid >= 256: V,  wave = 64 rows x 64 cols of C = Wv*x^T      (acc[4][4])
// Grid 448 x 256thr; ~190 regs/wave -> 2 waves/SIMD, all co-resident.
// Epilogue: per-wave private LDS transpose (same-wave ds ordering, no bar).
__global__ __launch_bounds__(256) void gemm3(
    const _Float16* __restrict__ xf, const _Float16* __restrict__ wqkf,
    const _Float16* __restrict__ wvf,
    _Float16* __restrict__ Qf, _Float16* __restrict__ Kf, _Float16* __restrict__ Vkt)
{
    __shared__ _Float16 Lds[4*1280];   // 10 KB: per-wave transpose scratch
    const int tid = threadIdx.x, lane = tid & 63, w = tid >> 6;
    const int c = lane & 15, quad = lane >> 4;
    const int bid = blockIdx.x;
    _Float16* L = &Lds[w*1280];        // 32x40 halves, wave-private

    if (bid < 256) {
        // ---- QK mode: 1024 waves, (mt64, nt96) = (u>>4, u&15) ----
        const int u = bid*4 + w;
        const int mt64 = u >> 4, nt96 = u & 15;
        const _Float16* Ab = xf   + (size_t)(mt64*4)*24*512 + (size_t)lane*8;
        const _Float16* Bb = wqkf + (size_t)(nt96*6)*24*512 + (size_t)lane*8;

        f32x4 acc[4][6] = {};
        f16x8 a0[4], b0[6], a1[4], b1[6];
        auto load0 = [&](int kt) {
#pragma unroll
            for (int i = 0; i < 4; ++i) a0[i] = *(const f16x8*)(Ab + ((size_t)(i*24 + kt))*512);
#pragma unroll
            for (int j = 0; j < 6; ++j) b0[j] = *(const f16x8*)(Bb + ((size_t)(j*24 + kt))*512);
        };
        auto load1 = [&](int kt) {
#pragma unroll
            for (int i = 0; i < 4; ++i) a1[i] = *(const f16x8*)(Ab + ((size_t)(i*24 + kt))*512);
#pragma unroll
            for (int j = 0; j < 6; ++j) b1[j] = *(const f16x8*)(Bb + ((size_t)(j*24 + kt))*512);
        };
        auto step0 = [&]() {
#pragma unroll
            for (int i = 0; i < 4; ++i)
#pragma unroll
                for (int j = 0; j < 6; ++j)
                    acc[i][j] = __builtin_amdgcn_mfma_f32_16x16x32_f16(a0[i], b0[j], acc[i][j], 0,0,0);
        };
        auto step1 = [&]() {
#pragma unroll
            for (int i = 0; i < 4; ++i)
#pragma unroll
                for (int j = 0; j < 6; ++j)
                    acc[i][j] = __builtin_amdgcn_mfma_f32_16x16x32_f16(a1[i], b1[j], acc[i][j], 0,0,0);
        };

        load0(0);
        for (int kt = 0; kt < 24; kt += 2) {
            load1(kt+1);            // prefetch odd step (covered by step0)
            step0();
            if (kt < 22) load0(kt+2);   // prefetch next even (covered by step1)
            step1();
        }

        // epilogue: 2x3 transposed 32x32 chunks -> Qf/Kf frag layout
#pragma unroll
        for (int i2 = 0; i2 < 2; ++i2)
#pragma unroll
            for (int j2 = 0; j2 < 3; ++j2) {
#pragma unroll
                for (int ii = 0; ii < 2; ++ii)
#pragma unroll
                    for (int jj = 0; jj < 2; ++jj)
#pragma unroll
                        for (int r = 0; r < 4; ++r)
                            L[(ii*16 + quad*4 + r)*40 + jj*16 + c] =
                                (_Float16)acc[i2*2+ii][j2*2+jj][r];
#pragma unroll
                for (int ii = 0; ii < 2; ++ii) {
                    const int mtg = mt64*4 + i2*2 + ii;   // 16-row unit
                    f16x8 v = *(const f16x8*)(L + (ii*16 + c)*40 + quad*8);
                    const int nt32 = nt96*3 + j2;         // 32-col unit
                    _Float16* dst = (nt32 < 24)
                        ? Qf + ((size_t)(mtg*24 + nt32)*64 + lane)*8
                        : Kf + ((size_t)(mtg*24 + nt32 - 24)*64 + lane)*8;
                    *(f16x8*)dst = v;
                }
            }
    } else {
        // ---- V mode: 768 waves, (mtv, ntv) = (u>>6, u&63) ----
        const int u = (bid - 256)*4 + w;
        const int mtv = u >> 6, ntv = u & 63;
        const _Float16* Ab = wvf + (size_t)(mtv*4)*24*512 + (size_t)lane*8;
        const _Float16* Bb = xf  + (size_t)(ntv*4)*24*512 + (size_t)lane*8;

        f32x4 acc[4][4] = {};
        f16x8 a0[4], b0[4], a1[4], b1[4];
        auto load0 = [&](int kt) {
#pragma unroll
            for (int i = 0; i < 4; ++i) a0[i] = *(const f16x8*)(Ab + ((size_t)(i*24 + kt))*512);
#pragma unroll
            for (int j = 0; j < 4; ++j) b0[j] = *(const f16x8*)(Bb + ((size_t)(j*24 + kt))*512);
        };
        auto load1 = [&](int kt) {
#pragma unroll
            for (int i = 0; i < 4; ++i) a1[i] = *(const f16x8*)(Ab + ((size_t)(i*24 + kt))*512);
#pragma unroll
            for (int j = 0; j < 4; ++j) b1[j] = *(const f16x8*)(Bb + ((size_t)(j*24 + kt))*512);
        };
        auto step0 = [&]() {
#pragma unroll
            for (int i = 0; i < 4; ++i)
#pragma unroll
                for (int j = 0; j < 4; ++j)
                    acc[i][j] = __builtin_amdgcn_mfma_f32_16x16x32_f16(a0[i], b0[j], acc[i][j], 0,0,0);
        };
        auto step1 = [&]() {
#pragma unroll
            for (int i = 0; i < 4; ++i)
#pragma unroll
                for (int j = 0; j < 4; ++j)
                    acc[i][j] = __builtin_amdgcn_mfma_f32_16x16x32_f16(a1[i], b1[j], acc[i][j], 0,0,0);
        };

        load0(0);
        for (int kt = 0; kt < 24; kt += 2) {
            load1(kt+1);
            step0();
            if (kt < 22) load0(kt+2);
            step1();
        }

        // epilogue: 2x2 transposed 32x32 chunks -> Vkt 16x16 tiles
#pragma unroll
        for (int i2 = 0; i2 < 2; ++i2)
#pragma unroll
            for (int j2 = 0; j2 < 2; ++j2) {
#pragma unroll
                for (int ii = 0; ii < 2; ++ii)
#pragma unroll
                    for (int jj = 0; jj < 2; ++jj)
#pragma unroll
                        for (int r = 0; r < 4; ++r)
                            L[(ii*16 + quad*4 + r)*40 + jj*16 + c] =
                                (_Float16)acc[i2*2+ii][j2*2+jj][r];
#pragma unroll
                for (int ii = 0; ii < 2; ++ii) {
                    const int mtg = mtv*4 + i2*2 + ii;    // 16-row unit (d)
#pragma unroll
                    for (int jj = 0; jj < 2; ++jj) {
                        f16x4 v4 = *(const f16x4*)(L + (ii*16 + c)*40 + jj*16 + quad*4);
                        const int kcu = ntv*4 + j2*2 + jj;   // 16-key unit
                        *(f16x4*)(Vkt + ((size_t)kcu*48 + mtg)*256 + lane*4) = v4;
                    }
                }
            }
    }
}

// ---- fused attention = EXACT v11/v13 kernel (87.5-89.6 us, best measured) ----
// Pl stride 20 (stride-24 measured 4.7x MORE conflicts); no XCD swizzle
// (L2 replication across XCDs beats locality for the L2-BW-bound V stream).
// grid: 512 blocks (2/CU), 512 thr (8 waves: qi=w>>2 in {0,1}, g=w&3).
// Block = 32 q-rows (2 qt) x 512 keys; 32 subtiles of 16 keys.
// LDS 50.7 KB (Kb 24K + Ps 10.5K + Pl 15K), ~112 regs/wave -> 2 blocks/CU.
// Per iter t: [ph1(t); Ps; ph2(t-1)] A [dma K(t+1); softmax; Pl; issue vv(t)] B
__global__ __launch_bounds__(512) __attribute__((amdgpu_waves_per_eu(4)))
void attn_kernel(
    const _Float16* __restrict__ Qf, const _Float16* __restrict__ Kf,
    const _Float16* __restrict__ Vkt,
    float* __restrict__ out,          // ks==0 partial (covers all elements)
    _Float16* __restrict__ part)      // [3][4096][768] f16, ks=1..3
{
    __shared__ __attribute__((aligned(16))) _Float16 Kb[24*512];        // 24 KB
    __shared__ __attribute__((aligned(16))) float    Ps[8][336];        // 10.5 KB
    __shared__ __attribute__((aligned(16))) _Float16 Pl[2][12][16][20]; // 15 KB
    const int tid = threadIdx.x, lane = tid & 63, w = tid >> 6;
    const int c = lane & 15, quad = lane >> 4;
    const int qi = w >> 2, g = w & 3;

    const int bid = blockIdx.x;
    const int qb = bid & 63;
    const int ks = (bid >> 6) & 3;
    const int b  = bid >> 8;
    const int qrow0 = b*SEQ + qb*32;
    const int qt16  = (qrow0 >> 4) + qi;
    const int kb16  = (b*SEQ + ks*(SEQ/KSPLIT)) >> 4;
    // Ps word offset: each 16-lane group touches one contiguous 256B region
    const int psoff = quad*84 + c*4;

    // Q frags (B-operand: b[lane][j] = Q[q=lane&15][d=quad*8+j]), heads 3g..3g+2
    f16x8 qreg[6];
#pragma unroll
    for (int u = 0; u < 6; ++u)
        qreg[u] = *(const f16x8*)(Qf + ((size_t)(qt16*24 + g*6 + u)*64 + lane)*8);

    // V base for this wave's d-tile: + (t*48 + h*4)*256 per (t,h)
    const _Float16* Vb0 = Vkt + ((size_t)kb16*48 + g)*256 + (size_t)lane*4;

    // preamble: DMA K(0) (all 8 waves, 3 frags each)
#pragma unroll
    for (int u = 0; u < 3; ++u)
        dma16(Kf + ((size_t)kb16*24 + w*3 + u)*512 + lane*8, &Kb[(w*3+u)*512]);
    __syncthreads();

    f32x4 o_acc[12] = {};   // 48 AGPRs: out^T[d=g*16+quad*4+r][q=c] per head
    f16x4 vv[12];           // V tiles for ph2, issued one iter ahead
    f32x4 e3[3];            // exp2(S^T) for own 3 heads

    for (int t = 0; t < 32; ++t) {
        // ---- ph1(t): S^T = K·Q for heads 3g..3g+2, exp2 in f32 regs ----
#pragma unroll
        for (int hh = 0; hh < 3; ++hh) {
            f16x8 ka = *(const f16x8*)(&Kb[(g*6 + hh*2    )*512] + lane*8);
            f16x8 k2 = *(const f16x8*)(&Kb[(g*6 + hh*2 + 1)*512] + lane*8);
            f32x4 a = {};
            a = __builtin_amdgcn_mfma_f32_16x16x32_f16(ka, qreg[hh*2],   a, 0,0,0);
            a = __builtin_amdgcn_mfma_f32_16x16x32_f16(k2, qreg[hh*2+1], a, 0,0,0);
            // a[r] = S^T[k = quad*4+r][q = c]  (log2 domain via Wq pre-scale)
            f32x4 ee;
#pragma unroll
            for (int r = 0; r < 4; ++r) ee[r] = __builtin_amdgcn_exp2f(a[r]);
            e3[hh] = ee;
        }
        {   // 3-head partial sum -> one b128 write
            f32x4 ps;
#pragma unroll
            for (int r = 0; r < 4; ++r) ps[r] = e3[0][r] + e3[1][r] + e3[2][r];
            *(f32x4*)&Ps[qi*4+g][psoff] = ps;
        }
        // ---- ph2(t-1): 12 heads x d-tile g over 16 keys ----
        if (t > 0) {
#pragma unroll
            for (int h = 0; h < 12; ++h) {
                f16x4 pf = *(const f16x4*)&Pl[qi][h][c][quad*4];
                o_acc[h] = __builtin_amdgcn_mfma_f32_16x16x16f16(vv[h], pf, o_acc[h], 0,0,0);
            }
        }
        __syncthreads();   // A: Ps visible; Kb/Pl readers done
        // ---- DMA K(t+1) (all 8 waves; Kb single-buffered, readers drained) ----
        if (t < 31) {
#pragma unroll
            for (int u = 0; u < 3; ++u)
                dma16(Kf + ((size_t)(kb16+t+1)*24 + w*3 + u)*512 + lane*8,
                      &Kb[(w*3+u)*512]);
        }
        // ---- softmax(t): total head-sum from 4 partials, P^T -> Pl ----
        {
            f32x4 s0 = *(const f32x4*)&Ps[qi*4+0][psoff];
            f32x4 s1 = *(const f32x4*)&Ps[qi*4+1][psoff];
            f32x4 s2 = *(const f32x4*)&Ps[qi*4+2][psoff];
            f32x4 s3 = *(const f32x4*)&Ps[qi*4+3][psoff];
            f32x4 inv;
#pragma unroll
            for (int r = 0; r < 4; ++r)
                inv[r] = __builtin_amdgcn_rcpf(
                    (s0[r]+s1[r]+s2[r]+s3[r]) * 27.712812921102035f);
#pragma unroll
            for (int hh = 0; hh < 3; ++hh) {
                f16x4 pw;
#pragma unroll
                for (int r = 0; r < 4; ++r) pw[r] = (_Float16)(e3[hh][r]*inv[r]);
                *(f16x4*)&Pl[qi][g*3+hh][c][quad*4] = pw;
            }
        }
        // ---- issue all 12 V tiles for ph2(t) (consumed next iter pre-A) ----
#pragma unroll
        for (int h = 0; h < 12; ++h)
            vv[h] = *(const f16x4*)(Vb0 + ((size_t)t*48 + h*4)*256);
        __syncthreads();   // B: Pl(t) visible; K(t+1) arrived
    }
    // ---- tail: ph2(31) ----
#pragma unroll
    for (int h = 0; h < 12; ++h) {
        f16x4 pf = *(const f16x4*)&Pl[qi][h][c][quad*4];
        o_acc[h] = __builtin_amdgcn_mfma_f32_16x16x16f16(vv[h], pf, o_acc[h], 0,0,0);
    }

    // ---- epilogue: o_acc[h][r] = out[q = c][d = h*64 + g*16 + quad*4 + r] ----
    if (ks == 0) {
#pragma unroll
        for (int h = 0; h < 12; ++h)
            *(f32x4*)(out + (size_t)(qrow0 + qi*16 + c)*DIM + h*64 + g*16 + quad*4)
                = o_acc[h];
    } else {
        _Float16* dst = part + (size_t)(ks - 1) * ROWS * DIM;
#pragma unroll
        for (int h = 0; h < 12; ++h) {
            f16x4 v;
#pragma unroll
            for (int r = 0; r < 4; ++r) v[r] = (_Float16)o_acc[h][r];
            *(f16x4*)(dst + (size_t)(qrow0 + qi*16 + c)*DIM + h*64 + g*16 + quad*4) = v;
        }
    }
}

// ---- out += sum of 3 f16 partials ----
__global__ __launch_bounds__(256) void reduce_add4(
    float* __restrict__ out, const _Float16* __restrict__ part, int n4)
{
    int i = blockIdx.x * 256 + threadIdx.x;
    if (i >= n4) return;
    float4 o = reinterpret_cast<float4*>(out)[i];
    const size_t N = (size_t)ROWS * DIM;
#pragma unroll
    for (int p = 0; p < 3; ++p) {
        f16x4 v = reinterpret_cast<const f16x4*>(part + p * N)[i];
        o.x += (float)v[0]; o.y += (float)v[1]; o.z += (float)v[2]; o.w += (float)v[3];
    }
    reinterpret_cast<float4*>(out)[i] = o;
}

// ------------------------------- launch ----------------------------------
extern "C" void kernel_launch(void* const* d_in, const int* in_sizes, int n_in,
                              void* d_out, int out_size, void* d_ws, size_t ws_size,
                              hipStream_t stream)
{
    const float* x  = (const float*)d_in[0];
    const float* Wq = (const float*)d_in[1];
    const float* Wk = (const float*)d_in[2];
    const float* Wv = (const float*)d_in[3];

    _Float16* ws  = (_Float16*)d_ws;
    const size_t XS = (size_t)ROWS * DIM;   // 3145728
    const size_t WS = (size_t)DIM * DIM;    // 589824
    _Float16* xf   = ws;
    _Float16* wqf  = xf  + XS;              // wq+wk adjacent = stacked [Wq;Wk]
    _Float16* wkf  = wqf + WS;
    _Float16* wvf  = wkf + WS;
    _Float16* Qf   = wvf + WS;
    _Float16* Kf   = Qf  + XS;
    _Float16* Vkt  = Kf  + XS;
    _Float16* part = Vkt + XS;              // 3 * XS f16 partials

    cvt_all<<<2400, 256, 0, stream>>>(x, Wq, Wk, Wv, xf, wqf, wkf, wvf);
    gemm3<<<448, 256, 0, stream>>>(xf, wqf, wvf, Qf, Kf, Vkt);
    attn_kernel<<<BATCH * KSPLIT * 64, 512, 0, stream>>>(
        Qf, Kf, Vkt, (float*)d_out, part);
    reduce_add4<<<(int)(XS/4 + 255)/256, 256, 0, stream>>>(
        (float*)d_out, part, (int)(XS/4));
}

// Round 17
// 176.157 us; speedup vs baseline: 1.0535x; 1.0535x over previous
//
#include <hip/hip_runtime.h>

#define DIM 768
#define NHEADS 12
#define HDIM 64
#define BATCH 2
#define SEQ 2048
#define ROWS (BATCH*SEQ)   // 4096
#define KSPLIT 4

typedef __attribute__((ext_vector_type(8))) _Float16 f16x8;
typedef __attribute__((ext_vector_type(4))) _Float16 f16x4;
typedef __attribute__((ext_vector_type(2))) _Float16 f16x2;
typedef __attribute__((ext_vector_type(4))) float    f32x4;

// async global->LDS DMA, 16 B per lane; LDS dest must be wave-uniform base
__device__ __forceinline__ void dma16(const _Float16* g, _Float16* l) {
    __builtin_amdgcn_global_load_lds(
        (const __attribute__((address_space(1))) unsigned int*)g,
        (__attribute__((address_space(3))) unsigned int*)l, 16, 0, 0);
}

// ============================================================
// Fragment layout F(mt, kt): 16 rows x 32 cols of row-major M[R][C]:
//   frag[lane][j] = M[mt*16 + (lane&15)][kt*32 + (lane>>4)*8 + j]
// stored at dst[((mt*(C/32) + kt)*64 + lane)*8] (halves).
// V tile layout (for 16x16x16 PV MFMA): per 16-key chunk kc,
//   Vkt[((kc*48 + (h*4+dt))*64 + lane)*4] : tile[lane][j] =
//   V[d = (h*4+dt)*16 + (lane&15)][key = kc*16 + (lane>>4)*4 + j]
// ============================================================

// ---- all 4 fp32->f16 frag conversions in one launch (all have C=768) ----
// Wq is pre-scaled by log2(e): QK^T scores land in log2 domain, so the
// softmax exp is a single v_exp_f32 (2^x). Wq feeds ONLY Q. (verified v4/v5)
__global__ __launch_bounds__(256) void cvt_all(
    const float* __restrict__ x,  const float* __restrict__ wq,
    const float* __restrict__ wk, const float* __restrict__ wv,
    _Float16* __restrict__ xf,  _Float16* __restrict__ wqf,
    _Float16* __restrict__ wkf, _Float16* __restrict__ wvf)
{
    const int lane = threadIdx.x & 63;
    const int wid  = (blockIdx.x * 256 + threadIdx.x) >> 6;
    const float* src; _Float16* dst; int t;
    float sc = 1.0f;
    if (wid < 6144)      { src = x;  dst = xf;  t = wid;        }
    else if (wid < 7296) { src = wq; dst = wqf; t = wid - 6144; sc = 1.4426950408889634f; }
    else if (wid < 8448) { src = wk; dst = wkf; t = wid - 7296; }
    else                 { src = wv; dst = wvf; t = wid - 8448; }
    const int c = lane & 15, quad = lane >> 4;
    const int mt = t / 24, kt = t % 24;
    const float* p = src + (size_t)(mt*16 + c) * 768 + kt*32 + quad*8;
    float4 v0 = *(const float4*)p;
    float4 v1 = *(const float4*)(p + 4);
    f16x8 o;
    o[0]=(_Float16)(v0.x*sc); o[1]=(_Float16)(v0.y*sc); o[2]=(_Float16)(v0.z*sc); o[3]=(_Float16)(v0.w*sc);
    o[4]=(_Float16)(v1.x*sc); o[5]=(_Float16)(v1.y*sc); o[6]=(_Float16)(v1.z*sc); o[7]=(_Float16)(v1.w*sc);
    *reinterpret_cast<f16x8*>(dst + ((size_t)t * 64 + lane) * 8) = o;
}

// ---- all 3 projections, v16: half-height tiles -> 2 blocks/CU overlap ----
// v14 ran ONE 8-wave barrier domain per CU: every per-K-step vmcnt+barrier
// idled the whole CU (same disease attn's v5 fixed with 2 blocks/CU).
// Halve tile rows, 256 thr / 4 waves per block:
// bid < 256: QK, 128x192 tiles (32x8 grid): C = x*[Wq;Wk]^T -> Qf/Kf.
//   Wave w: rows (w>>1)*64, cols (w&1)*96 -> acc[4][6].
//   Staging: 8 A + 12 B = 20 units, exactly 5/wave -> uniform vmcnt(5).
// bid >= 256: V, 128x128 tiles (6x32 grid): C = Wv*x^T -> Vkt.
//   Wave w: rows (w>>1)*64, cols (w&1)*64 -> acc[4][4].
//   Staging: 8 A + 8 B = 16 units, exactly 4/wave -> uniform vmcnt(4).
// 3-deep buffers + counted vmcnt (v12, verified): tile k+1 complete at the
// barrier, tile k+2 stays in flight with a full K-step of cover.
// LDS: QK 60 KB, V 48 KB -> 2 blocks/CU co-resident (<=120 KB, 8 waves/CU);
// one block's barrier stall overlaps the other block's MFMA.
__global__ __launch_bounds__(256) void gemm3(
    const _Float16* __restrict__ xf, const _Float16* __restrict__ wqkf,
    const _Float16* __restrict__ wvf,
    _Float16* __restrict__ Qf, _Float16* __restrict__ Kf, _Float16* __restrict__ Vkt)
{
    __shared__ _Float16 Ab[3][8*512];    // 24 KB (A: 8 row-units, 3-deep)
    __shared__ _Float16 Bb[3][12*512];   // 36 KB (B: up to 12 col-units, 3-deep)
    const int tid = threadIdx.x, lane = tid & 63, w = tid >> 6;
    const int c = lane & 15, quad = lane >> 4;
    const int bid = blockIdx.x;

    const _Float16 *Af, *Bf;
    int mt0, nt0, mode, upw;   // upw = staging units per wave
    if (bid < 256) {
        int mt = bid >> 3, nt = bid & 7;      // 32x8 tiles
        Af = xf; Bf = wqkf; mt0 = mt*8; nt0 = nt*12; mode = 0; upw = 5;
    } else {
        int v = bid - 256;
        int mt = v >> 5, nt = v & 31;         // 6x32 tiles
        Af = wvf; Bf = xf; mt0 = mt*8; nt0 = nt*8; mode = 1; upw = 4;
    }

    auto stage = [&](int kt, int buf) {
        for (int u = 0; u < upw; ++u) {
            const int cc = w*upw + u;
            const _Float16* s = (cc < 8) ? Af + ((size_t)(mt0+cc)*24 + kt)*512
                                         : Bf + ((size_t)(nt0+cc-8)*24 + kt)*512;
            _Float16* d = (cc < 8) ? &Ab[buf][cc*512] : &Bb[buf][(cc-8)*512];
            dma16(s + lane*8, d);
        }
    };

    // prologue: tile0 -> buf0, tile1 -> buf1; wait tile0 only (tile1 floats)
    stage(0, 0);
    stage(1, 1);
    if (mode == 0) asm volatile("s_waitcnt vmcnt(5) lgkmcnt(0)" ::: "memory");
    else           asm volatile("s_waitcnt vmcnt(4) lgkmcnt(0)" ::: "memory");
    asm volatile("s_barrier" ::: "memory");

    if (mode == 0) {
        f32x4 acc[4][6] = {};
        for (int kt = 0; kt < 24; ++kt) {
            const int cur = kt % 3;
            if (kt < 22) stage(kt+2, (kt+2) % 3);
            f16x8 a[4], b[6];
#pragma unroll
            for (int i = 0; i < 4; ++i)
                a[i] = *(const f16x8*)(&Ab[cur][((w>>1)*4 + i)*512] + lane*8);
#pragma unroll
            for (int j = 0; j < 6; ++j)
                b[j] = *(const f16x8*)(&Bb[cur][((w&1)*6 + j)*512] + lane*8);
#pragma unroll
            for (int i = 0; i < 4; ++i)
#pragma unroll
                for (int j = 0; j < 6; ++j)
                    acc[i][j] = __builtin_amdgcn_mfma_f32_16x16x32_f16(a[i], b[j], acc[i][j], 0,0,0);
            if (kt < 22) asm volatile("s_waitcnt vmcnt(5) lgkmcnt(0)" ::: "memory");
            else         asm volatile("s_waitcnt vmcnt(0) lgkmcnt(0)" ::: "memory");
            asm volatile("s_barrier" ::: "memory");
        }
        // epilogue: per-wave 64x96 as 2x3 transposed 32x32 chunks (wave-
        // private scratch; all loop reads drained at the final barrier)
        _Float16* L = &Ab[0][0] + w*1280;   // 32x40 halves per wave
#pragma unroll
        for (int i2 = 0; i2 < 2; ++i2)
#pragma unroll
            for (int j2 = 0; j2 < 3; ++j2) {
#pragma unroll
                for (int ii = 0; ii < 2; ++ii)
#pragma unroll
                    for (int jj = 0; jj < 2; ++jj)
#pragma unroll
                        for (int r = 0; r < 4; ++r)
                            L[(ii*16 + quad*4 + r)*40 + jj*16 + c] =
                                (_Float16)acc[i2*2+ii][j2*2+jj][r];
#pragma unroll
                for (int ii = 0; ii < 2; ++ii) {
                    const int mtg = mt0 + (w>>1)*4 + i2*2 + ii;   // 16-row unit
                    f16x8 v = *(const f16x8*)(L + (ii*16 + c)*40 + quad*8);
                    const int nt32 = (nt0 + (w&1)*6)/2 + j2;      // 32-col unit
                    _Float16* dst = (nt32 < 24)
                        ? Qf + ((size_t)(mtg*24 + nt32)*64 + lane)*8
                        : Kf + ((size_t)(mtg*24 + nt32 - 24)*64 + lane)*8;
                    *(f16x8*)dst = v;
                }
            }
    } else {
        f32x4 acc[4][4] = {};
        for (int kt = 0; kt < 24; ++kt) {
            const int cur = kt % 3;
            if (kt < 22) stage(kt+2, (kt+2) % 3);
            f16x8 a[4], b[4];
#pragma unroll
            for (int i = 0; i < 4; ++i)
                a[i] = *(const f16x8*)(&Ab[cur][((w>>1)*4 + i)*512] + lane*8);
#pragma unroll
            for (int j = 0; j < 4; ++j)
                b[j] = *(const f16x8*)(&Bb[cur][((w&1)*4 + j)*512] + lane*8);
#pragma unroll
            for (int i = 0; i < 4; ++i)
#pragma unroll
                for (int j = 0; j < 4; ++j)
                    acc[i][j] = __builtin_amdgcn_mfma_f32_16x16x32_f16(a[i], b[j], acc[i][j], 0,0,0);
            if (kt < 22) asm volatile("s_waitcnt vmcnt(4) lgkmcnt(0)" ::: "memory");
            else         asm volatile("s_waitcnt vmcnt(0) lgkmcnt(0)" ::: "memory");
            asm volatile("s_barrier" ::: "memory");
        }
        // epilogue: per-wave 32x32 transposes -> Vkt tiles (verified path)
        _Float16* L = &Ab[0][0] + w*1280;   // 32x40 halves per wave
#pragma unroll
        for (int i2 = 0; i2 < 2; ++i2)
#pragma unroll
            for (int j2 = 0; j2 < 2; ++j2) {
#pragma unroll
                for (int ii = 0; ii < 2; ++ii)
#pragma unroll
                    for (int jj = 0; jj < 2; ++jj)
#pragma unroll
                        for (int r = 0; r < 4; ++r)
                            L[(ii*16 + quad*4 + r)*40 + jj*16 + c] =
                                (_Float16)acc[i2*2+ii][j2*2+jj][r];
#pragma unroll
                for (int ii = 0; ii < 2; ++ii) {
                    const int mtg = mt0 + (w>>1)*4 + i2*2 + ii;   // 16-row unit (d)
#pragma unroll
                    for (int jj = 0; jj < 2; ++jj) {
                        f16x4 v4 = *(const f16x4*)(L + (ii*16 + c)*40 + jj*16 + quad*4);
                        const int kcu = nt0 + (w&1)*4 + j2*2 + jj;   // 16-key unit
                        *(f16x4*)(Vkt + ((size_t)kcu*48 + mtg)*256 + lane*4) = v4;
                    }
                }
            }
    }
}

// ---- fused attention = EXACT v11/v13 kernel (87.5-89.6 us, best measured) ----
// Pl stride 20 (stride-24 measured 4.7x MORE conflicts); no XCD swizzle
// (L2 replication across XCDs beats locality for the L2-BW-bound V stream).
// grid: 512 blocks (2/CU), 512 thr (8 waves: qi=w>>2 in {0,1}, g=w&3).
// Block = 32 q-rows (2 qt) x 512 keys; 32 subtiles of 16 keys.
// LDS 50.7 KB (Kb 24K + Ps 10.5K + Pl 15K), ~112 regs/wave -> 2 blocks/CU.
// Per iter t: [ph1(t); Ps; ph2(t-1)] A [dma K(t+1); softmax; Pl; issue vv(t)] B
__global__ __launch_bounds__(512) __attribute__((amdgpu_waves_per_eu(4)))
void attn_kernel(
    const _Float16* __restrict__ Qf, const _Float16* __restrict__ Kf,
    const _Float16* __restrict__ Vkt,
    float* __restrict__ out,          // ks==0 partial (covers all elements)
    _Float16* __restrict__ part)      // [3][4096][768] f16, ks=1..3
{
    __shared__ __attribute__((aligned(16))) _Float16 Kb[24*512];        // 24 KB
    __shared__ __attribute__((aligned(16))) float    Ps[8][336];        // 10.5 KB
    __shared__ __attribute__((aligned(16))) _Float16 Pl[2][12][16][20]; // 15 KB
    const int tid = threadIdx.x, lane = tid & 63, w = tid >> 6;
    const int c = lane & 15, quad = lane >> 4;
    const int qi = w >> 2, g = w & 3;

    const int bid = blockIdx.x;
    const int qb = bid & 63;
    const int ks = (bid >> 6) & 3;
    const int b  = bid >> 8;
    const int qrow0 = b*SEQ + qb*32;
    const int qt16  = (qrow0 >> 4) + qi;
    const int kb16  = (b*SEQ + ks*(SEQ/KSPLIT)) >> 4;
    // Ps word offset: each 16-lane group touches one contiguous 256B region
    const int psoff = quad*84 + c*4;

    // Q frags (B-operand: b[lane][j] = Q[q=lane&15][d=quad*8+j]), heads 3g..3g+2
    f16x8 qreg[6];
#pragma unroll
    for (int u = 0; u < 6; ++u)
        qreg[u] = *(const f16x8*)(Qf + ((size_t)(qt16*24 + g*6 + u)*64 + lane)*8);

    // V base for this wave's d-tile: + (t*48 + h*4)*256 per (t,h)
    const _Float16* Vb0 = Vkt + ((size_t)kb16*48 + g)*256 + (size_t)lane*4;

    // preamble: DMA K(0) (all 8 waves, 3 frags each)
#pragma unroll
    for (int u = 0; u < 3; ++u)
        dma16(Kf + ((size_t)kb16*24 + w*3 + u)*512 + lane*8, &Kb[(w*3+u)*512]);
    __syncthreads();

    f32x4 o_acc[12] = {};   // 48 AGPRs: out^T[d=g*16+quad*4+r][q=c] per head
    f16x4 vv[12];           // V tiles for ph2, issued one iter ahead
    f32x4 e3[3];            // exp2(S^T) for own 3 heads

    for (int t = 0; t < 32; ++t) {
        // ---- ph1(t): S^T = K·Q for heads 3g..3g+2, exp2 in f32 regs ----
#pragma unroll
        for (int hh = 0; hh < 3; ++hh) {
            f16x8 ka = *(const f16x8*)(&Kb[(g*6 + hh*2    )*512] + lane*8);
            f16x8 k2 = *(const f16x8*)(&Kb[(g*6 + hh*2 + 1)*512] + lane*8);
            f32x4 a = {};
            a = __builtin_amdgcn_mfma_f32_16x16x32_f16(ka, qreg[hh*2],   a, 0,0,0);
            a = __builtin_amdgcn_mfma_f32_16x16x32_f16(k2, qreg[hh*2+1], a, 0,0,0);
            // a[r] = S^T[k = quad*4+r][q = c]  (log2 domain via Wq pre-scale)
            f32x4 ee;
#pragma unroll
            for (int r = 0; r < 4; ++r) ee[r] = __builtin_amdgcn_exp2f(a[r]);
            e3[hh] = ee;
        }
        {   // 3-head partial sum -> one b128 write
            f32x4 ps;
#pragma unroll
            for (int r = 0; r < 4; ++r) ps[r] = e3[0][r] + e3[1][r] + e3[2][r];
            *(f32x4*)&Ps[qi*4+g][psoff] = ps;
        }
        // ---- ph2(t-1): 12 heads x d-tile g over 16 keys ----
        if (t > 0) {
#pragma unroll
            for (int h = 0; h < 12; ++h) {
                f16x4 pf = *(const f16x4*)&Pl[qi][h][c][quad*4];
                o_acc[h] = __builtin_amdgcn_mfma_f32_16x16x16f16(vv[h], pf, o_acc[h], 0,0,0);
            }
        }
        __syncthreads();   // A: Ps visible; Kb/Pl readers done
        // ---- DMA K(t+1) (all 8 waves; Kb single-buffered, readers drained) ----
        if (t < 31) {
#pragma unroll
            for (int u = 0; u < 3; ++u)
                dma16(Kf + ((size_t)(kb16+t+1)*24 + w*3 + u)*512 + lane*8,
                      &Kb[(w*3+u)*512]);
        }
        // ---- softmax(t): total head-sum from 4 partials, P^T -> Pl ----
        {
            f32x4 s0 = *(const f32x4*)&Ps[qi*4+0][psoff];
            f32x4 s1 = *(const f32x4*)&Ps[qi*4+1][psoff];
            f32x4 s2 = *(const f32x4*)&Ps[qi*4+2][psoff];
            f32x4 s3 = *(const f32x4*)&Ps[qi*4+3][psoff];
            f32x4 inv;
#pragma unroll
            for (int r = 0; r < 4; ++r)
                inv[r] = __builtin_amdgcn_rcpf(
                    (s0[r]+s1[r]+s2[r]+s3[r]) * 27.712812921102035f);
#pragma unroll
            for (int hh = 0; hh < 3; ++hh) {
                f16x4 pw;
#pragma unroll
                for (int r = 0; r < 4; ++r) pw[r] = (_Float16)(e3[hh][r]*inv[r]);
                *(f16x4*)&Pl[qi][g*3+hh][c][quad*4] = pw;
            }
        }
        // ---- issue all 12 V tiles for ph2(t) (consumed next iter pre-A) ----
#pragma unroll
        for (int h = 0; h < 12; ++h)
            vv[h] = *(const f16x4*)(Vb0 + ((size_t)t*48 + h*4)*256);
        __syncthreads();   // B: Pl(t) visible; K(t+1) arrived
    }
    // ---- tail: ph2(31) ----
#pragma unroll
    for (int h = 0; h < 12; ++h) {
        f16x4 pf = *(const f16x4*)&Pl[qi][h][c][quad*4];
        o_acc[h] = __builtin_amdgcn_mfma_f32_16x16x16f16(vv[h], pf, o_acc[h], 0,0,0);
    }

    // ---- epilogue: o_acc[h][r] = out[q = c][d = h*64 + g*16 + quad*4 + r] ----
    if (ks == 0) {
#pragma unroll
        for (int h = 0; h < 12; ++h)
            *(f32x4*)(out + (size_t)(qrow0 + qi*16 + c)*DIM + h*64 + g*16 + quad*4)
                = o_acc[h];
    } else {
        _Float16* dst = part + (size_t)(ks - 1) * ROWS * DIM;
#pragma unroll
        for (int h = 0; h < 12; ++h) {
            f16x4 v;
#pragma unroll
            for (int r = 0; r < 4; ++r) v[r] = (_Float16)o_acc[h][r];
            *(f16x4*)(dst + (size_t)(qrow0 + qi*16 + c)*DIM + h*64 + g*16 + quad*4) = v;
        }
    }
}

// ---- out += sum of 3 f16 partials ----
__global__ __launch_bounds__(256) void reduce_add4(
    float* __restrict__ out, const _Float16* __restrict__ part, int n4)
{
    int i = blockIdx.x * 256 + threadIdx.x;
    if (i >= n4) return;
    float4 o = reinterpret_cast<float4*>(out)[i];
    const size_t N = (size_t)ROWS * DIM;
#pragma unroll
    for (int p = 0; p < 3; ++p) {
        f16x4 v = reinterpret_cast<const f16x4*>(part + p * N)[i];
        o.x += (float)v[0]; o.y += (float)v[1]; o.z += (float)v[2]; o.w += (float)v[3];
    }
    reinterpret_cast<float4*>(out)[i] = o;
}

// ------------------------------- launch ----------------------------------
extern "C" void kernel_launch(void* const* d_in, const int* in_sizes, int n_in,
                              void* d_out, int out_size, void* d_ws, size_t ws_size,
                              hipStream_t stream)
{
    const float* x  = (const float*)d_in[0];
    const float* Wq = (const float*)d_in[1];
    const float* Wk = (const float*)d_in[2];
    const float* Wv = (const float*)d_in[3];

    _Float16* ws  = (_Float16*)d_ws;
    const size_t XS = (size_t)ROWS * DIM;   // 3145728
    const size_t WS = (size_t)DIM * DIM;    // 589824
    _Float16* xf   = ws;
    _Float16* wqf  = xf  + XS;              // wq+wk adjacent = stacked [Wq;Wk]
    _Float16* wkf  = wqf + WS;
    _Float16* wvf  = wkf + WS;
    _Float16* Qf   = wvf + WS;
    _Float16* Kf   = Qf  + XS;
    _Float16* Vkt  = Kf  + XS;
    _Float16* part = Vkt + XS;              // 3 * XS f16 partials

    cvt_all<<<2400, 256, 0, stream>>>(x, Wq, Wk, Wv, xf, wqf, wkf, wvf);
    gemm3<<<448, 256, 0, stream>>>(xf, wqf, wvf, Qf, Kf, Vkt);
    attn_kernel<<<BATCH * KSPLIT * 64, 512, 0, stream>>>(
        Qf, Kf, Vkt, (float*)d_out, part);
    reduce_add4<<<(int)(XS/4 + 255)/256, 256, 0, stream>>>(
        (float*)d_out, part, (int)(XS/4));
}